// Round 15
// baseline (676.836 us; speedup 1.0000x reference)
//
#include <hip/hip_runtime.h>
#include <hip/hip_bf16.h>
#include <stdint.h>

typedef __bf16 bf16x8 __attribute__((ext_vector_type(8)));
typedef float f32x4 __attribute__((ext_vector_type(4)));

#define GLDS16(gp, lp) __builtin_amdgcn_global_load_lds( \
    (const __attribute__((address_space(1))) unsigned int*)(gp), \
    (__attribute__((address_space(3))) unsigned int*)(lp), 16, 0, 0)

#define BARRIER() asm volatile("s_barrier" ::: "memory")
#define VMCNT(n)  asm volatile("s_waitcnt vmcnt(" #n ")" ::: "memory")

// ---------------- precompute: xg = bf16(x * g), wsgn = bf16(sign(w)) ----------------

__global__ __launch_bounds__(256) void prep_xg(
    const float* __restrict__ x, const float* __restrict__ g,
    __bf16* __restrict__ out, long total, int K)
{
    long i = ((long)blockIdx.x * blockDim.x + threadIdx.x) * 8;
    const long stride = (long)gridDim.x * blockDim.x * 8;
    for (; i < total; i += stride) {
        const int k = (int)(i & (long)(K - 1));
        f32x4 x0 = *(const f32x4*)(x + i);
        f32x4 x1 = *(const f32x4*)(x + i + 4);
        f32x4 g0 = *(const f32x4*)(g + k);
        f32x4 g1 = *(const f32x4*)(g + k + 4);
        bf16x8 o;
        #pragma unroll
        for (int j = 0; j < 4; ++j) o[j]     = (__bf16)(x0[j] * g0[j]);
        #pragma unroll
        for (int j = 0; j < 4; ++j) o[4 + j] = (__bf16)(x1[j] * g1[j]);
        *(bf16x8*)(out + i) = o;
    }
}

__global__ __launch_bounds__(256) void prep_sign(
    const float* __restrict__ w, __bf16* __restrict__ out, long total)
{
    long i = ((long)blockIdx.x * blockDim.x + threadIdx.x) * 8;
    const long stride = (long)gridDim.x * blockDim.x * 8;
    for (; i < total; i += stride) {
        f32x4 w0 = *(const f32x4*)(w + i);
        f32x4 w1 = *(const f32x4*)(w + i + 4);
        bf16x8 o;
        #pragma unroll
        for (int j = 0; j < 4; ++j)
            o[j]     = (__bf16)((w0[j] > 0.f) ? 1.f : ((w0[j] < 0.f) ? -1.f : 0.f));
        #pragma unroll
        for (int j = 0; j < 4; ++j)
            o[4 + j] = (__bf16)((w1[j] > 0.f) ? 1.f : ((w1[j] < 0.f) ? -1.f : 0.f));
        *(bf16x8*)(out + i) = o;
    }
}

// ---------------- 256x256 bf16 GEMM, 1024 threads, 4x4 waves, BK=32, ring-4 ----------------
// 16 waves = 4 waves/SIMD: within a barrier interval, waves whose frag reads retire
// first start MFMA while others still queue on LDS -> implicit LDS||MFMA overlap the
// 2-wave/SIMD structures could not reach (6 schedule variants, all ~50% MfmaUtil).
// Per wave: 64x64 output -> acc 4x4 f32x4 (64 AGPR) + 8 b128 frags (32 VGPR) -> fits
// 128-reg budget for 4 waves/SIMD.
// Staging: one GLDS16 per operand tile (1024 thr x 16B = 16 KB); 4-lane group = one
// full 64B cacheline of one row. Ring-4 buffers (32 KB each) = 128 KB.
// XOR swizzle both sides (verified r11/r12, 0 conflicts): key=(row>>1)&3;
//   src chunk=(t&3)^((t>>3)&3), linear dest; read chunk = sl^((fr>>1)&3).
// Ledger: prologue stages t0,t1,t2 (6 instr); iter top VMCNT(4) retires tile t
// (tail VMCNT(2)/VMCNT(0)); BARRIER; stage t+3 into buf (t+3)&3 whose tile-(t-1)
// readers drained before the previous barrier (r11 WAR argument, passed 2x).

template<bool BF16OUT>
__global__ __launch_bounds__(1024, 4) void gemm_w4(
    const __bf16* __restrict__ A, const __bf16* __restrict__ B,
    const float* __restrict__ bias, const float* __restrict__ h,
    __bf16* __restrict__ yb, float* __restrict__ yf, int M, int N, int K)
{
    extern __shared__ __bf16 sm[];   // 4 * 16384 elems = 128 KB

    // XCD order: bn-minor, bm-major. grid = (M/256)*(N/256) = 1024.
    const int xcd = blockIdx.x & 7;
    const int l = blockIdx.x >> 3;
    const int bn = xcd * 2 + (l & 1);
    const int bm = l >> 1;

    const int t = threadIdx.x;              // 0..1023
    const int lane = t & 63;
    const int w = t >> 6;                   // 16 waves
    const int wm = w >> 2;                  // 4: rows [wm*64, +64)
    const int wn = w & 3;                   // 4: cols [wn*64, +64)
    const int sl = lane >> 4;               // k-chunk 0..3
    const int fr = lane & 15;
    const int swz = (sl ^ ((fr >> 1) & 3)) * 8;   // frag-read swizzled chunk (elems)

    const int row8 = t >> 2;                      // 0..255
    const int chS = ((t & 3) ^ ((t >> 3) & 3)) * 8;

    const __bf16* gA = A + (long)(bm * 256 + row8) * K + chS;
    const __bf16* gB = B + (long)(bn * 256 + row8) * K + chS;

    const int NT = K / 32;   // 128

#define STG(b, T) do { \
    GLDS16(gA + (long)(T) * 32, &sm[(b) * 16384 + t * 8]); \
    GLDS16(gB + (long)(T) * 32, &sm[(b) * 16384 + 8192 + t * 8]); \
} while (0)

#define RD_A(dst, b, m)  dst = *(bf16x8*)&sm[(b) * 16384 + (wm * 64 + (m) * 16 + fr) * 32 + swz]
#define RD_B(dst, b, n)  dst = *(bf16x8*)&sm[(b) * 16384 + 8192 + (wn * 64 + (n) * 16 + fr) * 32 + swz]
#define MF(d, a, b) d = __builtin_amdgcn_mfma_f32_16x16x32_bf16(a, b, d, 0, 0, 0)

    f32x4 acc[4][4] = {};

    // ---- prologue: stage tiles 0,1,2 into buffers 0,1,2 ----
    STG(0, 0); STG(1, 1); STG(2, 2);

    for (int ti = 0; ti < NT; ++ti) {
        const int b = ti & 3;

        if (ti < NT - 2)       VMCNT(4);
        else if (ti == NT - 2) VMCNT(2);
        else                   VMCNT(0);
        BARRIER();

        if (ti + 3 < NT) STG((ti + 3) & 3, ti + 3);

        bf16x8 af[4], bf[4];
        #pragma unroll
        for (int m = 0; m < 4; ++m) RD_A(af[m], b, m);
        #pragma unroll
        for (int n = 0; n < 4; ++n) RD_B(bf[n], b, n);

        __builtin_amdgcn_s_setprio(1);
        #pragma unroll
        for (int m = 0; m < 4; ++m)
            #pragma unroll
            for (int n = 0; n < 4; ++n) MF(acc[m][n], af[m], bf[n]);
        __builtin_amdgcn_s_setprio(0);
    }

    // ---- epilogue: y = (acc + bias) * h, nontemporal ----
    const int cr = (lane >> 4) * 4;
    const int cc = lane & 15;
    #pragma unroll
    for (int n = 0; n < 4; ++n) {
        const int col = bn * 256 + wn * 64 + n * 16 + cc;
        const float bc = bias[col];
        const float hc = h[col];
        #pragma unroll
        for (int m = 0; m < 4; ++m) {
            const long rowb = (long)bm * 256 + wm * 64 + m * 16 + cr;
            #pragma unroll
            for (int j = 0; j < 4; ++j) {
                const float v = (acc[m][n][j] + bc) * hc;
                if (BF16OUT) {
                    union { __bf16 b; unsigned short u; } cv;
                    cv.b = (__bf16)v;
                    __builtin_nontemporal_store(cv.u,
                        (unsigned short*)yb + (rowb + j) * (long)N + col);
                } else {
                    __builtin_nontemporal_store(v, yf + (rowb + j) * (long)N + col);
                }
            }
        }
    }
#undef STG
#undef RD_A
#undef RD_B
#undef MF
}

// ---------------- LayerNorm: read bf16 row-pair from WS, write f32 to d_out ----------------

__global__ __launch_bounds__(256) void ln_ws(
    const __bf16* __restrict__ ybuf, float* __restrict__ out,
    const float* __restrict__ gamma, const float* __restrict__ beta)
{
    const long r0 = (long)blockIdx.x * 2;
    const int t = threadIdx.x;
    const int lane = t & 63, wave = t >> 6;

    bf16x8 a0 = *(const bf16x8*)(ybuf + r0 * 4096 + t * 16);
    bf16x8 a1 = *(const bf16x8*)(ybuf + r0 * 4096 + t * 16 + 8);
    bf16x8 b0 = *(const bf16x8*)(ybuf + (r0 + 1) * 4096 + t * 16);
    bf16x8 b1 = *(const bf16x8*)(ybuf + (r0 + 1) * 4096 + t * 16 + 8);

    float v0[16], v1[16];
    float s0 = 0.f, q0 = 0.f, s1 = 0.f, q1 = 0.f;
    #pragma unroll
    for (int j = 0; j < 8; ++j) {
        v0[j] = (float)a0[j]; v0[8 + j] = (float)a1[j];
        v1[j] = (float)b0[j]; v1[8 + j] = (float)b1[j];
    }
    #pragma unroll
    for (int j = 0; j < 16; ++j) {
        s0 += v0[j]; q0 += v0[j] * v0[j];
        s1 += v1[j]; q1 += v1[j] * v1[j];
    }
    #pragma unroll
    for (int off = 32; off > 0; off >>= 1) {
        s0 += __shfl_down(s0, off); q0 += __shfl_down(q0, off);
        s1 += __shfl_down(s1, off); q1 += __shfl_down(q1, off);
    }
    __shared__ float red[4][4];
    if (lane == 0) { red[wave][0] = s0; red[wave][1] = q0; red[wave][2] = s1; red[wave][3] = q1; }
    __syncthreads();
    const float ts0 = red[0][0] + red[1][0] + red[2][0] + red[3][0];
    const float tq0 = red[0][1] + red[1][1] + red[2][1] + red[3][1];
    const float ts1 = red[0][2] + red[1][2] + red[2][2] + red[3][2];
    const float tq1 = red[0][3] + red[1][3] + red[2][3] + red[3][3];
    const float mu0 = ts0 * (1.0f / 4096.0f);
    const float mu1 = ts1 * (1.0f / 4096.0f);
    const float rs0 = rsqrtf(tq0 * (1.0f / 4096.0f) - mu0 * mu0 + 1e-5f);
    const float rs1 = rsqrtf(tq1 * (1.0f / 4096.0f) - mu1 * mu1 + 1e-5f);

    #pragma unroll
    for (int c = 0; c < 4; ++c) {
        f32x4 gv = *(const f32x4*)(gamma + t * 16 + c * 4);
        f32x4 bv = *(const f32x4*)(beta + t * 16 + c * 4);
        f32x4 o0, o1;
        #pragma unroll
        for (int j = 0; j < 4; ++j) {
            o0[j] = (v0[c * 4 + j] - mu0) * rs0 * gv[j] + bv[j];
            o1[j] = (v1[c * 4 + j] - mu1) * rs1 * gv[j] + bv[j];
        }
        *(f32x4*)(out + r0 * 4096 + t * 16 + c * 4) = o0;
        *(f32x4*)(out + (r0 + 1) * 4096 + t * 16 + c * 4) = o1;
    }
}

// ---------------- f32 in-place LN (verified) ----------------

__global__ __launch_bounds__(256) void ln_inplace(
    float* __restrict__ y, const float* __restrict__ gamma,
    const float* __restrict__ beta, int N)
{
    const long row = blockIdx.x;
    float* p = y + row * (long)N;
    const int t = threadIdx.x;

    f32x4 v[4];
    float sum = 0.f, sq = 0.f;
    #pragma unroll
    for (int i = 0; i < 4; ++i) {
        v[i] = *(const f32x4*)(p + i * 1024 + t * 4);
        #pragma unroll
        for (int j = 0; j < 4; ++j) { sum += v[i][j]; sq += v[i][j] * v[i][j]; }
    }
    #pragma unroll
    for (int off = 32; off > 0; off >>= 1) {
        sum += __shfl_down(sum, off);
        sq  += __shfl_down(sq, off);
    }
    __shared__ float s1[4], s2[4];
    const int lane = t & 63, wave = t >> 6;
    if (lane == 0) { s1[wave] = sum; s2[wave] = sq; }
    __syncthreads();
    const float tot = s1[0] + s1[1] + s1[2] + s1[3];
    const float tsq = s2[0] + s2[1] + s2[2] + s2[3];
    const float mean = tot / (float)N;
    const float var = tsq / (float)N - mean * mean;
    const float rstd = rsqrtf(var + 1e-5f);

    #pragma unroll
    for (int i = 0; i < 4; ++i) {
        f32x4 ga = *(const f32x4*)(gamma + i * 1024 + t * 4);
        f32x4 be = *(const f32x4*)(beta + i * 1024 + t * 4);
        f32x4 o;
        #pragma unroll
        for (int j = 0; j < 4; ++j) o[j] = (v[i][j] - mean) * rstd * ga[j] + be[j];
        *(f32x4*)(p + i * 1024 + t * 4) = o;
    }
}

// ---------------- fallback (round-0 fused path, used only if shape/ws unsuitable) ----------------

#define BMf 128
#define BNf 128
#define BKf 32
#define LDPf 40

__global__ __launch_bounds__(256) void binlin_gemm_fb(
    const float* __restrict__ x, const float* __restrict__ w,
    const float* __restrict__ bias, const float* __restrict__ g,
    const float* __restrict__ h, float* __restrict__ y,
    int M, int N, int K)
{
    __shared__ __bf16 As[BMf][LDPf];
    __shared__ __bf16 Bs[BNf][LDPf];
    const int nbn = N / BNf;
    const int bm = blockIdx.x / nbn;
    const int bn = blockIdx.x % nbn;
    const int t = threadIdx.x;
    const int lane = t & 63;
    const int wave = t >> 6;
    const int wm = wave >> 1, wn = wave & 1;
    const int row2 = t >> 2, kq = (t & 3) * 8;
    const long xbase = (long)bm * BMf * K;
    const long wbase = (long)bn * BNf * K;
    f32x4 acc[4][4] = {};
    const int fr = lane & 15;
    const int ko = (lane >> 4) * 8;
    for (int k0 = 0; k0 < K; k0 += BKf) {
        f32x4 ga = *(const f32x4*)(g + k0 + kq);
        f32x4 gb = *(const f32x4*)(g + k0 + kq + 4);
        #pragma unroll
        for (int p = 0; p < 2; ++p) {
            const int r = p * 64 + row2;
            const float* xp = x + xbase + (long)r * K + k0 + kq;
            f32x4 x0 = *(const f32x4*)xp;
            f32x4 x1 = *(const f32x4*)(xp + 4);
            bf16x8 av;
            #pragma unroll
            for (int i = 0; i < 4; ++i) av[i]     = (__bf16)(x0[i] * ga[i]);
            #pragma unroll
            for (int i = 0; i < 4; ++i) av[4 + i] = (__bf16)(x1[i] * gb[i]);
            *(bf16x8*)&As[r][kq] = av;
            const float* wp = w + wbase + (long)r * K + k0 + kq;
            f32x4 w0 = *(const f32x4*)wp;
            f32x4 w1 = *(const f32x4*)(wp + 4);
            bf16x8 bv;
            #pragma unroll
            for (int i = 0; i < 4; ++i)
                bv[i]     = (__bf16)((w0[i] > 0.f) ? 1.f : ((w0[i] < 0.f) ? -1.f : 0.f));
            #pragma unroll
            for (int i = 0; i < 4; ++i)
                bv[4 + i] = (__bf16)((w1[i] > 0.f) ? 1.f : ((w1[i] < 0.f) ? -1.f : 0.f));
            *(bf16x8*)&Bs[r][kq] = bv;
        }
        __syncthreads();
        bf16x8 af[4], bfr[4];
        #pragma unroll
        for (int m = 0; m < 4; ++m) af[m]  = *(bf16x8*)&As[wm * 64 + m * 16 + fr][ko];
        #pragma unroll
        for (int n = 0; n < 4; ++n) bfr[n] = *(bf16x8*)&Bs[wn * 64 + n * 16 + fr][ko];
        #pragma unroll
        for (int m = 0; m < 4; ++m)
            #pragma unroll
            for (int n = 0; n < 4; ++n)
                acc[m][n] = __builtin_amdgcn_mfma_f32_16x16x32_bf16(af[m], bfr[n], acc[m][n], 0, 0, 0);
        __syncthreads();
    }
    const int cr = (lane >> 4) * 4;
    const int cc = lane & 15;
    #pragma unroll
    for (int n = 0; n < 4; ++n) {
        const int col = bn * BNf + wn * 64 + n * 16 + cc;
        const float bc = bias[col];
        const float hc = h[col];
        #pragma unroll
        for (int m = 0; m < 4; ++m) {
            const long rowb = (long)bm * BMf + wm * 64 + m * 16 + cr;
            #pragma unroll
            for (int j = 0; j < 4; ++j)
                y[(rowb + j) * N + col] = (acc[m][n][j] + bc) * hc;
        }
    }
}

extern "C" void kernel_launch(void* const* d_in, const int* in_sizes, int n_in,
                              void* d_out, int out_size, void* d_ws, size_t ws_size,
                              hipStream_t stream)
{
    (void)n_in; (void)out_size;
    const float* x     = (const float*)d_in[0];
    const float* w     = (const float*)d_in[1];
    const float* bias  = (const float*)d_in[2];
    const float* g     = (const float*)d_in[3];
    const float* h     = (const float*)d_in[4];
    const float* gamma = (const float*)d_in[5];
    const float* beta  = (const float*)d_in[6];
    float* out = (float*)d_out;

    const int D = in_sizes[2];                 // 4096
    const long M = (long)in_sizes[0] / D;      // 16384

    const size_t needA = (size_t)M * D * sizeof(__bf16);   // 128 MB (xg)
    const size_t needB = (size_t)D * D * sizeof(__bf16);   //  32 MB (sign w)
    const size_t needY = (size_t)M * D * sizeof(__bf16);   // 128 MB (y bf16)

    const bool okShape = (D == 4096 && (M % 512) == 0);

    if (okShape && ws_size >= needA + needB) {
        __bf16* xg   = (__bf16*)d_ws;
        __bf16* wsgn = (__bf16*)((char*)d_ws + needA);
        prep_xg  <<<dim3(2048), dim3(256), 0, stream>>>(x, g, xg, M * (long)D, D);
        prep_sign<<<dim3(2048), dim3(256), 0, stream>>>(w, wsgn, (long)D * D);
        dim3 grid((unsigned)((M / 256) * (D / 256)));   // 1024

        if (ws_size >= needA + needB + needY) {
            __bf16* ybf = (__bf16*)((char*)d_ws + needA + needB);
            hipFuncSetAttribute((const void*)gemm_w4<true>,
                                hipFuncAttributeMaxDynamicSharedMemorySize, 131072);
            gemm_w4<true><<<grid, dim3(1024), 131072, stream>>>(
                xg, wsgn, bias, h, ybf, nullptr, (int)M, D, D);
            ln_ws<<<dim3((unsigned)(M / 2)), dim3(256), 0, stream>>>(ybf, out, gamma, beta);
        } else {
            hipFuncSetAttribute((const void*)gemm_w4<false>,
                                hipFuncAttributeMaxDynamicSharedMemorySize, 131072);
            gemm_w4<false><<<grid, dim3(1024), 131072, stream>>>(
                xg, wsgn, bias, h, nullptr, out, (int)M, D, D);
            ln_inplace<<<dim3((unsigned)M), dim3(256), 0, stream>>>(out, gamma, beta, D);
        }
    } else {
        dim3 grid((unsigned)((M / BMf) * (D / BNf)));
        binlin_gemm_fb<<<grid, dim3(256), 0, stream>>>(x, w, bias, g, h, out, (int)M, D, D);
        ln_inplace<<<dim3((unsigned)M), dim3(256), 0, stream>>>(out, gamma, beta, D);
    }
}

// Round 16
// 638.736 us; speedup vs baseline: 1.0596x; 1.0596x over previous
//
#include <hip/hip_runtime.h>
#include <hip/hip_bf16.h>
#include <stdint.h>

typedef __bf16 bf16x8 __attribute__((ext_vector_type(8)));
typedef float f32x4 __attribute__((ext_vector_type(4)));

#define GLDS16(gp, lp) __builtin_amdgcn_global_load_lds( \
    (const __attribute__((address_space(1))) unsigned int*)(gp), \
    (__attribute__((address_space(3))) unsigned int*)(lp), 16, 0, 0)

#define BARRIER() asm volatile("s_barrier" ::: "memory")
#define VMCNT(n)  asm volatile("s_waitcnt vmcnt(" #n ")" ::: "memory")

// ---------------- precompute: xg = bf16(x * g), wsgn = bf16(sign(w)) ----------------

__global__ __launch_bounds__(256) void prep_xg(
    const float* __restrict__ x, const float* __restrict__ g,
    __bf16* __restrict__ out, long total, int K)
{
    long i = ((long)blockIdx.x * blockDim.x + threadIdx.x) * 8;
    const long stride = (long)gridDim.x * blockDim.x * 8;
    for (; i < total; i += stride) {
        const int k = (int)(i & (long)(K - 1));
        f32x4 x0 = *(const f32x4*)(x + i);
        f32x4 x1 = *(const f32x4*)(x + i + 4);
        f32x4 g0 = *(const f32x4*)(g + k);
        f32x4 g1 = *(const f32x4*)(g + k + 4);
        bf16x8 o;
        #pragma unroll
        for (int j = 0; j < 4; ++j) o[j]     = (__bf16)(x0[j] * g0[j]);
        #pragma unroll
        for (int j = 0; j < 4; ++j) o[4 + j] = (__bf16)(x1[j] * g1[j]);
        *(bf16x8*)(out + i) = o;
    }
}

__global__ __launch_bounds__(256) void prep_sign(
    const float* __restrict__ w, __bf16* __restrict__ out, long total)
{
    long i = ((long)blockIdx.x * blockDim.x + threadIdx.x) * 8;
    const long stride = (long)gridDim.x * blockDim.x * 8;
    for (; i < total; i += stride) {
        f32x4 w0 = *(const f32x4*)(w + i);
        f32x4 w1 = *(const f32x4*)(w + i + 4);
        bf16x8 o;
        #pragma unroll
        for (int j = 0; j < 4; ++j)
            o[j]     = (__bf16)((w0[j] > 0.f) ? 1.f : ((w0[j] < 0.f) ? -1.f : 0.f));
        #pragma unroll
        for (int j = 0; j < 4; ++j)
            o[4 + j] = (__bf16)((w1[j] > 0.f) ? 1.f : ((w1[j] < 0.f) ? -1.f : 0.f));
        *(bf16x8*)(out + i) = o;
    }
}

// ---------------- 8-phase 256x256 bf16 GEMM, BK=64, 2 LDS buffers (r10 best config) ----------
// COALESCED staging: each 8-lane group loads 128 contiguous bytes of ONE row
// (2 full cachelines). LDS row-major [256][64] bf16; XOR swizzle both sides:
//   source chunk = (lane&7) ^ (lane>>3&7); read chunk = c ^ (fr&7) -> 2-way alias (free).
// Single barrier per phase; vmcnt(6) only at p3/p7 (verified ledger).

template<bool BF16OUT>
__global__ __launch_bounds__(512, 2) void gemm_8p(
    const __bf16* __restrict__ A, const __bf16* __restrict__ B,
    const float* __restrict__ bias, const float* __restrict__ h,
    __bf16* __restrict__ yb, float* __restrict__ yf, int M, int N, int K)
{
    extern __shared__ __bf16 sm[];   // 2 buffers x (A 16384 + B 16384) elems = 128 KB

    // XCD order: bn-minor, bm-major (B panels L2-resident, A shared via L3).
    const int xcd = blockIdx.x & 7;
    const int l = blockIdx.x >> 3;
    const int bn = xcd * 2 + (l & 1);
    const int bm = l >> 1;

    const int t = threadIdx.x;
    const int lane = t & 63;
    const int w = t >> 6;            // 8 waves: wm = w>>2 (2), wn = w&3 (4)
    const int wm = w >> 2;
    const int wn = w & 3;
    const int sl = lane >> 4;        // k-subslice 0..3
    const int fr = lane & 15;
    const int swzR = fr & 7;         // frag-read row swizzle key

    const int g8 = lane >> 3;                       // row within 8-row group
    const int swz8 = ((lane & 7) ^ g8) * 8;         // swizzled 16B-chunk (elems)

    const __bf16* gA = A + (long)(bm * 256 + w * 16 + g8) * K + swz8;
    const __bf16* gB = B + (long)(bn * 256 + w * 16 + g8) * K + swz8;

    const int NT = K / 64;           // 64 K-tiles

#define STG_A(c, T, half) do { \
    GLDS16(gA + (long)((half) * 128) * K + (long)(T) * 64, \
           &sm[(c) * 32768 + ((half) * 128 + w * 16) * 64 + lane * 8]); \
    GLDS16(gA + (long)((half) * 128 + 8) * K + (long)(T) * 64, \
           &sm[(c) * 32768 + ((half) * 128 + w * 16 + 8) * 64 + lane * 8]); \
} while (0)
#define STG_B(c, T, half) do { \
    GLDS16(gB + (long)((half) * 128) * K + (long)(T) * 64, \
           &sm[(c) * 32768 + 16384 + ((half) * 128 + w * 16) * 64 + lane * 8]); \
    GLDS16(gB + (long)((half) * 128 + 8) * K + (long)(T) * 64, \
           &sm[(c) * 32768 + 16384 + ((half) * 128 + w * 16 + 8) * 64 + lane * 8]); \
} while (0)

#define RD_A(dst, cb, m, kk)  dst = *(bf16x8*)&sm[(cb) + ((m) * 32 + wm * 16 + fr) * 64 + ((((kk) * 4 + sl)) ^ swzR) * 8]
#define RD_B(dst, cb, n, kk)  dst = *(bf16x8*)&sm[(cb) + 16384 + ((n) * 64 + wn * 16 + fr) * 64 + ((((kk) * 4 + sl)) ^ swzR) * 8]
#define MF(d, a, b) d = __builtin_amdgcn_mfma_f32_16x16x32_bf16(a, b, d, 0, 0, 0)

    f32x4 acc[8][4] = {};
    bf16x8 aF[4][2], aH[4][2], b0F[2][2], b1F[2][2];

    // ---- prologue: tile0 all 4 units -> buf0 ; tile1 Ah0,Bh0,Bh1 -> buf1 ----
    STG_A(0, 0, 0); STG_B(0, 0, 0); STG_B(0, 0, 1); STG_A(0, 0, 1);
    STG_A(1, 1, 0); STG_B(1, 1, 0); STG_B(1, 1, 1);
    VMCNT(6);
    BARRIER();

    for (int i = 0; i < NT / 2; ++i) {
        const int t1 = 2 * i + 1;
        const int nx0 = 2 * i + 2;
        const int nx1 = 2 * i + 3;
        const bool more = (nx0 < NT);

        // ================= tile t0 in buf0 =================
        // p0: read aF, b0F, b1F (16); q0 = acc[0..3][0..1] (aF,b0F)
        #pragma unroll
        for (int kk = 0; kk < 2; ++kk) {
            #pragma unroll
            for (int m = 0; m < 4; ++m) RD_A(aF[m][kk], 0, m, kk);
            #pragma unroll
            for (int n = 0; n < 2; ++n) RD_B(b0F[n][kk], 0, n, kk);
            #pragma unroll
            for (int n = 0; n < 2; ++n) RD_B(b1F[n][kk], 0, n + 2, kk);
        }
        STG_A(1, t1, 1);
        __builtin_amdgcn_s_setprio(1);
        #pragma unroll
        for (int kk = 0; kk < 2; ++kk)
            #pragma unroll
            for (int m = 0; m < 4; ++m)
                #pragma unroll
                for (int n = 0; n < 2; ++n) MF(acc[m][n], aF[m][kk], b0F[n][kk]);
        __builtin_amdgcn_s_setprio(0);
        BARRIER();

        // p1: read aH (8); q1 = acc[0..3][2..3] (aF,b1F)
        #pragma unroll
        for (int kk = 0; kk < 2; ++kk)
            #pragma unroll
            for (int m = 0; m < 4; ++m) RD_A(aH[m][kk], 0, m + 4, kk);
        if (more) STG_A(0, nx0, 0);
        __builtin_amdgcn_s_setprio(1);
        #pragma unroll
        for (int kk = 0; kk < 2; ++kk)
            #pragma unroll
            for (int m = 0; m < 4; ++m)
                #pragma unroll
                for (int n = 0; n < 2; ++n) MF(acc[m][n + 2], aF[m][kk], b1F[n][kk]);
        __builtin_amdgcn_s_setprio(0);
        BARRIER();

        // p2: no reads; q2 = acc[4..7][2..3] (aH,b1F)
        if (more) STG_B(0, nx0, 0);
        __builtin_amdgcn_s_setprio(1);
        #pragma unroll
        for (int kk = 0; kk < 2; ++kk)
            #pragma unroll
            for (int m = 0; m < 4; ++m)
                #pragma unroll
                for (int n = 0; n < 2; ++n) MF(acc[m + 4][n + 2], aH[m][kk], b1F[n][kk]);
        __builtin_amdgcn_s_setprio(0);
        BARRIER();

        // p3: no reads; q3 = acc[4..7][0..1] (aH,b0F); retiring vmcnt before barrier
        if (more) { STG_B(0, nx0, 1); VMCNT(6); } else { VMCNT(0); }
        __builtin_amdgcn_s_setprio(1);
        #pragma unroll
        for (int kk = 0; kk < 2; ++kk)
            #pragma unroll
            for (int m = 0; m < 4; ++m)
                #pragma unroll
                for (int n = 0; n < 2; ++n) MF(acc[m + 4][n], aH[m][kk], b0F[n][kk]);
        __builtin_amdgcn_s_setprio(0);
        BARRIER();

        // ================= tile t1 in buf1 =================
        // p4: read aF, b0F, b1F; q0
        #pragma unroll
        for (int kk = 0; kk < 2; ++kk) {
            #pragma unroll
            for (int m = 0; m < 4; ++m) RD_A(aF[m][kk], 32768, m, kk);
            #pragma unroll
            for (int n = 0; n < 2; ++n) RD_B(b0F[n][kk], 32768, n, kk);
            #pragma unroll
            for (int n = 0; n < 2; ++n) RD_B(b1F[n][kk], 32768, n + 2, kk);
        }
        if (more) STG_A(0, nx0, 1);
        __builtin_amdgcn_s_setprio(1);
        #pragma unroll
        for (int kk = 0; kk < 2; ++kk)
            #pragma unroll
            for (int m = 0; m < 4; ++m)
                #pragma unroll
                for (int n = 0; n < 2; ++n) MF(acc[m][n], aF[m][kk], b0F[n][kk]);
        __builtin_amdgcn_s_setprio(0);
        BARRIER();

        // p5: read aH; q1
        #pragma unroll
        for (int kk = 0; kk < 2; ++kk)
            #pragma unroll
            for (int m = 0; m < 4; ++m) RD_A(aH[m][kk], 32768, m + 4, kk);
        if (more) STG_A(1, nx1, 0);
        __builtin_amdgcn_s_setprio(1);
        #pragma unroll
        for (int kk = 0; kk < 2; ++kk)
            #pragma unroll
            for (int m = 0; m < 4; ++m)
                #pragma unroll
                for (int n = 0; n < 2; ++n) MF(acc[m][n + 2], aF[m][kk], b1F[n][kk]);
        __builtin_amdgcn_s_setprio(0);
        BARRIER();

        // p6: no reads; q2
        if (more) STG_B(1, nx1, 0);
        __builtin_amdgcn_s_setprio(1);
        #pragma unroll
        for (int kk = 0; kk < 2; ++kk)
            #pragma unroll
            for (int m = 0; m < 4; ++m)
                #pragma unroll
                for (int n = 0; n < 2; ++n) MF(acc[m + 4][n + 2], aH[m][kk], b1F[n][kk]);
        __builtin_amdgcn_s_setprio(0);
        BARRIER();

        // p7: no reads; q3
        if (more) { STG_B(1, nx1, 1); VMCNT(6); } else { VMCNT(0); }
        __builtin_amdgcn_s_setprio(1);
        #pragma unroll
        for (int kk = 0; kk < 2; ++kk)
            #pragma unroll
            for (int m = 0; m < 4; ++m)
                #pragma unroll
                for (int n = 0; n < 2; ++n) MF(acc[m + 4][n], aH[m][kk], b0F[n][kk]);
        __builtin_amdgcn_s_setprio(0);
        BARRIER();
    }

    // ---- epilogue: y = (acc + bias) * h, nontemporal ----
    const int cr = (lane >> 4) * 4;
    const int cc = lane & 15;
    #pragma unroll
    for (int n = 0; n < 4; ++n) {
        const int col = bn * 256 + n * 64 + wn * 16 + cc;
        const float bc = bias[col];
        const float hc = h[col];
        #pragma unroll
        for (int m = 0; m < 8; ++m) {
            const long rowb = (long)bm * 256 + m * 32 + wm * 16 + cr;
            #pragma unroll
            for (int j = 0; j < 4; ++j) {
                const float v = (acc[m][n][j] + bc) * hc;
                if (BF16OUT) {
                    union { __bf16 b; unsigned short u; } cv;
                    cv.b = (__bf16)v;
                    __builtin_nontemporal_store(cv.u,
                        (unsigned short*)yb + (rowb + j) * (long)N + col);
                } else {
                    __builtin_nontemporal_store(v, yf + (rowb + j) * (long)N + col);
                }
            }
        }
    }
#undef STG_A
#undef STG_B
#undef RD_A
#undef RD_B
#undef MF
}

// ---------------- LayerNorm: read bf16 row-pair from WS, write f32 to d_out ----------------

__global__ __launch_bounds__(256) void ln_ws(
    const __bf16* __restrict__ ybuf, float* __restrict__ out,
    const float* __restrict__ gamma, const float* __restrict__ beta)
{
    const long r0 = (long)blockIdx.x * 2;
    const int t = threadIdx.x;
    const int lane = t & 63, wave = t >> 6;

    bf16x8 a0 = *(const bf16x8*)(ybuf + r0 * 4096 + t * 16);
    bf16x8 a1 = *(const bf16x8*)(ybuf + r0 * 4096 + t * 16 + 8);
    bf16x8 b0 = *(const bf16x8*)(ybuf + (r0 + 1) * 4096 + t * 16);
    bf16x8 b1 = *(const bf16x8*)(ybuf + (r0 + 1) * 4096 + t * 16 + 8);

    float v0[16], v1[16];
    float s0 = 0.f, q0 = 0.f, s1 = 0.f, q1 = 0.f;
    #pragma unroll
    for (int j = 0; j < 8; ++j) {
        v0[j] = (float)a0[j]; v0[8 + j] = (float)a1[j];
        v1[j] = (float)b0[j]; v1[8 + j] = (float)b1[j];
    }
    #pragma unroll
    for (int j = 0; j < 16; ++j) {
        s0 += v0[j]; q0 += v0[j] * v0[j];
        s1 += v1[j]; q1 += v1[j] * v1[j];
    }
    #pragma unroll
    for (int off = 32; off > 0; off >>= 1) {
        s0 += __shfl_down(s0, off); q0 += __shfl_down(q0, off);
        s1 += __shfl_down(s1, off); q1 += __shfl_down(q1, off);
    }
    __shared__ float red[4][4];
    if (lane == 0) { red[wave][0] = s0; red[wave][1] = q0; red[wave][2] = s1; red[wave][3] = q1; }
    __syncthreads();
    const float ts0 = red[0][0] + red[1][0] + red[2][0] + red[3][0];
    const float tq0 = red[0][1] + red[1][1] + red[2][1] + red[3][1];
    const float ts1 = red[0][2] + red[1][2] + red[2][2] + red[3][2];
    const float tq1 = red[0][3] + red[1][3] + red[2][3] + red[3][3];
    const float mu0 = ts0 * (1.0f / 4096.0f);
    const float mu1 = ts1 * (1.0f / 4096.0f);
    const float rs0 = rsqrtf(tq0 * (1.0f / 4096.0f) - mu0 * mu0 + 1e-5f);
    const float rs1 = rsqrtf(tq1 * (1.0f / 4096.0f) - mu1 * mu1 + 1e-5f);

    #pragma unroll
    for (int c = 0; c < 4; ++c) {
        f32x4 gv = *(const f32x4*)(gamma + t * 16 + c * 4);
        f32x4 bv = *(const f32x4*)(beta + t * 16 + c * 4);
        f32x4 o0, o1;
        #pragma unroll
        for (int j = 0; j < 4; ++j) {
            o0[j] = (v0[c * 4 + j] - mu0) * rs0 * gv[j] + bv[j];
            o1[j] = (v1[c * 4 + j] - mu1) * rs1 * gv[j] + bv[j];
        }
        *(f32x4*)(out + r0 * 4096 + t * 16 + c * 4) = o0;
        *(f32x4*)(out + (r0 + 1) * 4096 + t * 16 + c * 4) = o1;
    }
}

// ---------------- f32 in-place LN (verified) ----------------

__global__ __launch_bounds__(256) void ln_inplace(
    float* __restrict__ y, const float* __restrict__ gamma,
    const float* __restrict__ beta, int N)
{
    const long row = blockIdx.x;
    float* p = y + row * (long)N;
    const int t = threadIdx.x;

    f32x4 v[4];
    float sum = 0.f, sq = 0.f;
    #pragma unroll
    for (int i = 0; i < 4; ++i) {
        v[i] = *(const f32x4*)(p + i * 1024 + t * 4);
        #pragma unroll
        for (int j = 0; j < 4; ++j) { sum += v[i][j]; sq += v[i][j] * v[i][j]; }
    }
    #pragma unroll
    for (int off = 32; off > 0; off >>= 1) {
        sum += __shfl_down(sum, off);
        sq  += __shfl_down(sq, off);
    }
    __shared__ float s1[4], s2[4];
    const int lane = t & 63, wave = t >> 6;
    if (lane == 0) { s1[wave] = sum; s2[wave] = sq; }
    __syncthreads();
    const float tot = s1[0] + s1[1] + s1[2] + s1[3];
    const float tsq = s2[0] + s2[1] + s2[2] + s2[3];
    const float mean = tot / (float)N;
    const float var = tsq / (float)N - mean * mean;
    const float rstd = rsqrtf(var + 1e-5f);

    #pragma unroll
    for (int i = 0; i < 4; ++i) {
        f32x4 ga = *(const f32x4*)(gamma + i * 1024 + t * 4);
        f32x4 be = *(const f32x4*)(beta + i * 1024 + t * 4);
        f32x4 o;
        #pragma unroll
        for (int j = 0; j < 4; ++j) o[j] = (v[i][j] - mean) * rstd * ga[j] + be[j];
        *(f32x4*)(p + i * 1024 + t * 4) = o;
    }
}

// ---------------- fallback (round-0 fused path, used only if shape/ws unsuitable) ----------------

#define BMf 128
#define BNf 128
#define BKf 32
#define LDPf 40

__global__ __launch_bounds__(256) void binlin_gemm_fb(
    const float* __restrict__ x, const float* __restrict__ w,
    const float* __restrict__ bias, const float* __restrict__ g,
    const float* __restrict__ h, float* __restrict__ y,
    int M, int N, int K)
{
    __shared__ __bf16 As[BMf][LDPf];
    __shared__ __bf16 Bs[BNf][LDPf];
    const int nbn = N / BNf;
    const int bm = blockIdx.x / nbn;
    const int bn = blockIdx.x % nbn;
    const int t = threadIdx.x;
    const int lane = t & 63;
    const int wave = t >> 6;
    const int wm = wave >> 1, wn = wave & 1;
    const int row2 = t >> 2, kq = (t & 3) * 8;
    const long xbase = (long)bm * BMf * K;
    const long wbase = (long)bn * BNf * K;
    f32x4 acc[4][4] = {};
    const int fr = lane & 15;
    const int ko = (lane >> 4) * 8;
    for (int k0 = 0; k0 < K; k0 += BKf) {
        f32x4 ga = *(const f32x4*)(g + k0 + kq);
        f32x4 gb = *(const f32x4*)(g + k0 + kq + 4);
        #pragma unroll
        for (int p = 0; p < 2; ++p) {
            const int r = p * 64 + row2;
            const float* xp = x + xbase + (long)r * K + k0 + kq;
            f32x4 x0 = *(const f32x4*)xp;
            f32x4 x1 = *(const f32x4*)(xp + 4);
            bf16x8 av;
            #pragma unroll
            for (int i = 0; i < 4; ++i) av[i]     = (__bf16)(x0[i] * ga[i]);
            #pragma unroll
            for (int i = 0; i < 4; ++i) av[4 + i] = (__bf16)(x1[i] * gb[i]);
            *(bf16x8*)&As[r][kq] = av;
            const float* wp = w + wbase + (long)r * K + k0 + kq;
            f32x4 w0 = *(const f32x4*)wp;
            f32x4 w1 = *(const f32x4*)(wp + 4);
            bf16x8 bv;
            #pragma unroll
            for (int i = 0; i < 4; ++i)
                bv[i]     = (__bf16)((w0[i] > 0.f) ? 1.f : ((w0[i] < 0.f) ? -1.f : 0.f));
            #pragma unroll
            for (int i = 0; i < 4; ++i)
                bv[4 + i] = (__bf16)((w1[i] > 0.f) ? 1.f : ((w1[i] < 0.f) ? -1.f : 0.f));
            *(bf16x8*)&Bs[r][kq] = bv;
        }
        __syncthreads();
        bf16x8 af[4], bfr[4];
        #pragma unroll
        for (int m = 0; m < 4; ++m) af[m]  = *(bf16x8*)&As[wm * 64 + m * 16 + fr][ko];
        #pragma unroll
        for (int n = 0; n < 4; ++n) bfr[n] = *(bf16x8*)&Bs[wn * 64 + n * 16 + fr][ko];
        #pragma unroll
        for (int m = 0; m < 4; ++m)
            #pragma unroll
            for (int n = 0; n < 4; ++n)
                acc[m][n] = __builtin_amdgcn_mfma_f32_16x16x32_bf16(af[m], bfr[n], acc[m][n], 0, 0, 0);
        __syncthreads();
    }
    const int cr = (lane >> 4) * 4;
    const int cc = lane & 15;
    #pragma unroll
    for (int n = 0; n < 4; ++n) {
        const int col = bn * BNf + wn * 64 + n * 16 + cc;
        const float bc = bias[col];
        const float hc = h[col];
        #pragma unroll
        for (int m = 0; m < 4; ++m) {
            const long rowb = (long)bm * BMf + wm * 64 + m * 16 + cr;
            #pragma unroll
            for (int j = 0; j < 4; ++j)
                y[(rowb + j) * N + col] = (acc[m][n][j] + bc) * hc;
        }
    }
}

extern "C" void kernel_launch(void* const* d_in, const int* in_sizes, int n_in,
                              void* d_out, int out_size, void* d_ws, size_t ws_size,
                              hipStream_t stream)
{
    (void)n_in; (void)out_size;
    const float* x     = (const float*)d_in[0];
    const float* w     = (const float*)d_in[1];
    const float* bias  = (const float*)d_in[2];
    const float* g     = (const float*)d_in[3];
    const float* h     = (const float*)d_in[4];
    const float* gamma = (const float*)d_in[5];
    const float* beta  = (const float*)d_in[6];
    float* out = (float*)d_out;

    const int D = in_sizes[2];                 // 4096
    const long M = (long)in_sizes[0] / D;      // 16384

    const size_t needA = (size_t)M * D * sizeof(__bf16);   // 128 MB (xg)
    const size_t needB = (size_t)D * D * sizeof(__bf16);   //  32 MB (sign w)
    const size_t needY = (size_t)M * D * sizeof(__bf16);   // 128 MB (y bf16)

    const bool okShape = (D == 4096 && (M % 512) == 0);

    if (okShape && ws_size >= needA + needB) {
        __bf16* xg   = (__bf16*)d_ws;
        __bf16* wsgn = (__bf16*)((char*)d_ws + needA);
        prep_xg  <<<dim3(2048), dim3(256), 0, stream>>>(x, g, xg, M * (long)D, D);
        prep_sign<<<dim3(2048), dim3(256), 0, stream>>>(w, wsgn, (long)D * D);
        dim3 grid((unsigned)((M / 256) * (D / 256)));

        if (ws_size >= needA + needB + needY) {
            __bf16* ybf = (__bf16*)((char*)d_ws + needA + needB);
            hipFuncSetAttribute((const void*)gemm_8p<true>,
                                hipFuncAttributeMaxDynamicSharedMemorySize, 131072);
            gemm_8p<true><<<grid, dim3(512), 131072, stream>>>(
                xg, wsgn, bias, h, ybf, nullptr, (int)M, D, D);
            ln_ws<<<dim3((unsigned)(M / 2)), dim3(256), 0, stream>>>(ybf, out, gamma, beta);
        } else {
            hipFuncSetAttribute((const void*)gemm_8p<false>,
                                hipFuncAttributeMaxDynamicSharedMemorySize, 131072);
            gemm_8p<false><<<grid, dim3(512), 131072, stream>>>(
                xg, wsgn, bias, h, nullptr, out, (int)M, D, D);
            ln_inplace<<<dim3((unsigned)M), dim3(256), 0, stream>>>(out, gamma, beta, D);
        }
    } else {
        dim3 grid((unsigned)((M / BMf) * (D / BNf)));
        binlin_gemm_fb<<<grid, dim3(256), 0, stream>>>(x, w, bias, g, h, out, (int)M, D, D);
        ln_inplace<<<dim3((unsigned)M), dim3(256), 0, stream>>>(out, gamma, beta, D);
    }
}